// Round 1
// 2721.883 us; speedup vs baseline: 1.2501x; 1.2501x over previous
//
#include <hip/hip_runtime.h>

#define T_TOK 8192
#define D_DIM 2048
#define E_EXP 8
#define I_DIM 4096
#define BK 64     // bf16 elements per K-step (128 B per row)
#define NMT 128   // m-tiles per expert in the new path (covers worst-case 2T rows)

typedef __attribute__((ext_vector_type(8))) short short8;            // 8 bf16 (4 VGPRs)
typedef __attribute__((ext_vector_type(8))) unsigned short ushort8;
typedef __attribute__((ext_vector_type(4))) float floatx4;

#define LDS_ST 56  // old-path LDS row stride in ushorts

__device__ __forceinline__ unsigned short f2bf(float f) {
    union { float f; unsigned int u; } v;
    v.f = f;
    return (unsigned short)((v.u + 0x7fffu + ((v.u >> 16) & 1u)) >> 16);  // RNE
}

__device__ __forceinline__ ushort8 cvt8(float4 a, float4 b) {
    ushort8 r;
    r[0] = f2bf(a.x); r[1] = f2bf(a.y); r[2] = f2bf(a.z); r[3] = f2bf(a.w);
    r[4] = f2bf(b.x); r[5] = f2bf(b.y); r[6] = f2bf(b.z); r[7] = f2bf(b.w);
    return r;
}

// async 16B global -> LDS (wave-uniform LDS base + lane*16; per-lane global src)
__device__ __forceinline__ void gload_lds16(const unsigned short* g, unsigned short* l) {
    __builtin_amdgcn_global_load_lds(
        (const __attribute__((address_space(1))) unsigned int*)g,
        (__attribute__((address_space(3))) unsigned int*)l,
        16, 0, 0);
}

// ---------------- fp32 -> bf16 bulk conversion (memory-bound) ----------------
__global__ __launch_bounds__(256) void cvt_kernel(const float* __restrict__ in,
                                                  unsigned short* __restrict__ out,
                                                  size_t n8)
{
    const size_t stride = (size_t)gridDim.x * 256;
    for (size_t i = (size_t)blockIdx.x * 256 + threadIdx.x; i < n8; i += stride) {
        const float4* p = reinterpret_cast<const float4*>(in + i * 8);
        float4 a = p[0], b = p[1];
        *reinterpret_cast<ushort8*>(out + i * 8) = cvt8(a, b);
    }
}

// ---------------- router: logits -> softmax -> top2 (fp32 exact) ----------------
__global__ __launch_bounds__(256) void router_kernel(
    const float* __restrict__ h, const float* __restrict__ rw,
    int* __restrict__ topk_id, float* __restrict__ topk_w)
{
    const int t = blockIdx.x * 4 + (threadIdx.x >> 6);  // one wave per token
    const int lane = threadIdx.x & 63;
    const float* hp = h + (size_t)t * D_DIM;
    float acc[E_EXP];
#pragma unroll
    for (int e = 0; e < E_EXP; ++e) acc[e] = 0.f;
    for (int d = lane; d < D_DIM; d += 64) {
        float hv = hp[d];
#pragma unroll
        for (int e = 0; e < E_EXP; ++e) acc[e] += hv * rw[e * D_DIM + d];
    }
#pragma unroll
    for (int e = 0; e < E_EXP; ++e)
        for (int o = 32; o > 0; o >>= 1) acc[e] += __shfl_xor(acc[e], o, 64);
    if (lane == 0) {
        float mx = acc[0];
#pragma unroll
        for (int e = 1; e < E_EXP; ++e) mx = fmaxf(mx, acc[e]);
        float p[E_EXP]; float s = 0.f;
#pragma unroll
        for (int e = 0; e < E_EXP; ++e) { p[e] = __expf(acc[e] - mx); s += p[e]; }
        int i1 = 0;
#pragma unroll
        for (int e = 1; e < E_EXP; ++e) if (p[e] > p[i1]) i1 = e;
        int i2 = (i1 == 0) ? 1 : 0;
#pragma unroll
        for (int e = 0; e < E_EXP; ++e) if (e != i1 && p[e] > p[i2]) i2 = e;
        float inv = 1.f / s;
        topk_id[t * 2]     = i1; topk_w[t * 2]     = p[i1] * inv;
        topk_id[t * 2 + 1] = i2; topk_w[t * 2 + 1] = p[i2] * inv;
    }
}

// ---------------- routing bookkeeping ----------------
__global__ void count_kernel(const int* __restrict__ topk_id, int* __restrict__ cnt)
{
    const int i = blockIdx.x * 256 + threadIdx.x;  // over 2T entries
    atomicAdd(&cnt[topk_id[i]], 1);
}

__global__ void prefix_kernel(const int* __restrict__ cnt, int* __restrict__ off)
{
    int s = 0;
    for (int e = 0; e < E_EXP; ++e) { off[e] = s; s += cnt[e]; }
}

__global__ void scatter_kernel(const int* __restrict__ topk_id, const float* __restrict__ topk_w,
                               const int* __restrict__ off, int* __restrict__ cnt2,
                               int* __restrict__ tok_row, float* __restrict__ wt_row)
{
    const int i = blockIdx.x * 256 + threadIdx.x;  // over 2T entries
    const int e = topk_id[i];
    const int slot = atomicAdd(&cnt2[e], 1);
    const int rr = off[e] + slot;
    tok_row[rr] = i >> 1;
    wt_row[rr] = topk_w[i];
}

// =====================================================================
// NEW PATH: bf16 operands in global, global_load_lds staging, swizzled LDS
// Swizzle: 16B chunk c of row r holds logical chunk c ^ (r&7); LDS dest is
// linear (required by global_load_lds), the global SOURCE address is
// pre-swizzled, and ds_reads apply the same XOR (rule #21, m173/m201).
// =====================================================================

// ---- GEMM1: act = silu(h@Wg^T) * (h@Wu^T), 128x128 tile, fused gate/up ----
__global__ __launch_bounds__(256) void gateup2(
    const unsigned short* __restrict__ hb, const unsigned short* __restrict__ wsb,
    const int* __restrict__ tok_row, const int* __restrict__ cnt,
    const int* __restrict__ off, unsigned short* __restrict__ act)
{
    const int e  = blockIdx.y >> 7;
    const int mt = blockIdx.y & (NMT - 1);
    const int ce = cnt[e];
    if (mt * 128 >= ce) return;
    const int nt = blockIdx.x;
    const int base = off[e];

    __shared__ unsigned short As[128 * BK];
    __shared__ unsigned short Bg[128 * BK];
    __shared__ unsigned short Bu[128 * BK];

    const int tid  = threadIdx.x;
    const int wave = tid >> 6;
    const int lane = tid & 63;
    const int quad = lane >> 4;
    const int l16  = lane & 15;
    const int wm = (wave >> 1) * 64;
    const int wn = (wave & 1) * 64;

    // staging: wave w owns tile rows [w*32, w*32+32) in 4 calls of 8 rows
    const unsigned short* asrc[4];
    const unsigned short* gsrc[4];
    const unsigned short* usrc[4];
    unsigned short* adst[4];
    unsigned short* gdst[4];
    unsigned short* udst[4];
#pragma unroll
    for (int c = 0; c < 4; ++c) {
        const int row   = wave * 32 + c * 8 + (lane >> 3);      // tile row 0..127
        const int chunk = (lane & 7) ^ (row & 7);               // logical chunk to fetch
        int ar = mt * 128 + row;
        if (ar >= ce) ar = ce - 1;
        asrc[c] = hb + (size_t)tok_row[base + ar] * D_DIM + chunk * 8;
        const unsigned short* g =
            wsb + ((size_t)e * (2 * I_DIM) + (size_t)(nt * 128 + row)) * D_DIM + chunk * 8;
        gsrc[c] = g;
        usrc[c] = g + (size_t)I_DIM * D_DIM;
        adst[c] = &As[(wave * 32 + c * 8) * BK];
        gdst[c] = &Bg[(wave * 32 + c * 8) * BK];
        udst[c] = &Bu[(wave * 32 + c * 8) * BK];
    }

    floatx4 accg[4][4], accu[4][4];
#pragma unroll
    for (int i = 0; i < 4; ++i)
#pragma unroll
        for (int j = 0; j < 4; ++j) { accg[i][j] = (floatx4)0.f; accu[i][j] = (floatx4)0.f; }

    for (int k0 = 0; k0 < D_DIM; k0 += BK) {
        __syncthreads();   // previous tile fully consumed
#pragma unroll
        for (int c = 0; c < 4; ++c) {
            gload_lds16(asrc[c] + k0, adst[c]);
            gload_lds16(gsrc[c] + k0, gdst[c]);
            gload_lds16(usrc[c] + k0, udst[c]);
        }
        __syncthreads();   // implicit vmcnt(0) drain: loads landed
#pragma unroll
        for (int kk = 0; kk < 2; ++kk) {
            short8 a[4], bg[4], bu[4];
#pragma unroll
            for (int i = 0; i < 4; ++i) {
                const int row  = wm + i * 16 + l16;
                const int phys = ((kk * 4 + quad) ^ (row & 7)) << 3;
                a[i] = *reinterpret_cast<const short8*>(&As[row * BK + phys]);
            }
#pragma unroll
            for (int j = 0; j < 4; ++j) {
                const int row  = wn + j * 16 + l16;
                const int phys = ((kk * 4 + quad) ^ (row & 7)) << 3;
                bg[j] = *reinterpret_cast<const short8*>(&Bg[row * BK + phys]);
                bu[j] = *reinterpret_cast<const short8*>(&Bu[row * BK + phys]);
            }
#pragma unroll
            for (int i = 0; i < 4; ++i)
#pragma unroll
                for (int j = 0; j < 4; ++j) {
                    accg[i][j] = __builtin_amdgcn_mfma_f32_16x16x32_bf16(a[i], bg[j], accg[i][j], 0, 0, 0);
                    accu[i][j] = __builtin_amdgcn_mfma_f32_16x16x32_bf16(a[i], bu[j], accu[i][j], 0, 0, 0);
                }
        }
    }

    // epilogue: act = silu(gate) * up, bf16 store
#pragma unroll
    for (int i = 0; i < 4; ++i) {
#pragma unroll
        for (int reg = 0; reg < 4; ++reg) {
            const int gr = mt * 128 + wm + i * 16 + quad * 4 + reg;
            if (gr < ce) {
                const size_t rowoff = (size_t)(base + gr) * I_DIM;
#pragma unroll
                for (int j = 0; j < 4; ++j) {
                    float g = accg[i][j][reg];
                    float u = accu[i][j][reg];
                    float sa = g * u / (1.f + __expf(-g));
                    act[rowoff + nt * 128 + wn + j * 16 + l16] = f2bf(sa);
                }
            }
        }
    }
}

// ---- GEMM2: out[tok] += w * (act @ w2b[e]^T), 128x128 tile ----
__global__ __launch_bounds__(256) void down2(
    const unsigned short* __restrict__ act, const unsigned short* __restrict__ w2b,
    const int* __restrict__ tok_row, const float* __restrict__ wt_row,
    const int* __restrict__ cnt, const int* __restrict__ off,
    float* __restrict__ out)
{
    const int e  = blockIdx.y >> 7;
    const int mt = blockIdx.y & (NMT - 1);
    const int ce = cnt[e];
    if (mt * 128 >= ce) return;
    const int nt = blockIdx.x;
    const int base = off[e];

    __shared__ unsigned short As[128 * BK];
    __shared__ unsigned short Bs[128 * BK];

    const int tid  = threadIdx.x;
    const int wave = tid >> 6;
    const int lane = tid & 63;
    const int quad = lane >> 4;
    const int l16  = lane & 15;
    const int wm = (wave >> 1) * 64;
    const int wn = (wave & 1) * 64;

    const unsigned short* asrc[4];
    const unsigned short* bsrc[4];
    unsigned short* adst[4];
    unsigned short* bdst[4];
#pragma unroll
    for (int c = 0; c < 4; ++c) {
        const int row   = wave * 32 + c * 8 + (lane >> 3);
        const int chunk = (lane & 7) ^ (row & 7);
        int ar = mt * 128 + row;
        if (ar >= ce) ar = ce - 1;
        asrc[c] = act + (size_t)(base + ar) * I_DIM + chunk * 8;
        bsrc[c] = w2b + ((size_t)e * D_DIM + (size_t)(nt * 128 + row)) * I_DIM + chunk * 8;
        adst[c] = &As[(wave * 32 + c * 8) * BK];
        bdst[c] = &Bs[(wave * 32 + c * 8) * BK];
    }

    floatx4 acc[4][4];
#pragma unroll
    for (int i = 0; i < 4; ++i)
#pragma unroll
        for (int j = 0; j < 4; ++j) acc[i][j] = (floatx4)0.f;

    for (int k0 = 0; k0 < I_DIM; k0 += BK) {
        __syncthreads();
#pragma unroll
        for (int c = 0; c < 4; ++c) {
            gload_lds16(asrc[c] + k0, adst[c]);
            gload_lds16(bsrc[c] + k0, bdst[c]);
        }
        __syncthreads();
#pragma unroll
        for (int kk = 0; kk < 2; ++kk) {
            short8 a[4], b[4];
#pragma unroll
            for (int i = 0; i < 4; ++i) {
                const int row  = wm + i * 16 + l16;
                const int phys = ((kk * 4 + quad) ^ (row & 7)) << 3;
                a[i] = *reinterpret_cast<const short8*>(&As[row * BK + phys]);
            }
#pragma unroll
            for (int j = 0; j < 4; ++j) {
                const int row  = wn + j * 16 + l16;
                const int phys = ((kk * 4 + quad) ^ (row & 7)) << 3;
                b[j] = *reinterpret_cast<const short8*>(&Bs[row * BK + phys]);
            }
#pragma unroll
            for (int i = 0; i < 4; ++i)
#pragma unroll
                for (int j = 0; j < 4; ++j)
                    acc[i][j] = __builtin_amdgcn_mfma_f32_16x16x32_bf16(a[i], b[j], acc[i][j], 0, 0, 0);
        }
    }

#pragma unroll
    for (int i = 0; i < 4; ++i) {
#pragma unroll
        for (int reg = 0; reg < 4; ++reg) {
            const int gr = mt * 128 + wm + i * 16 + quad * 4 + reg;
            if (gr < ce) {
                const int tok = tok_row[base + gr];
                const float w = wt_row[base + gr];
                float* op = out + (size_t)tok * D_DIM + nt * 128 + wn;
#pragma unroll
                for (int j = 0; j < 4; ++j)
                    atomicAdd(&op[j * 16 + l16], acc[i][j][reg] * w);
            }
        }
    }
}

// =====================================================================
// OLD PATH (fallback when workspace too small): verified-passing kernels
// =====================================================================
__global__ __launch_bounds__(256) void gateup_kernel(
    const float* __restrict__ h, const float* __restrict__ ws,
    const int* __restrict__ tok_row, const int* __restrict__ cnt,
    const int* __restrict__ off, unsigned short* __restrict__ act)
{
    const int e  = blockIdx.y >> 6;
    const int mt = blockIdx.y & 63;
    const int ce = cnt[e];
    if (mt * 128 >= ce) return;
    const int nt = blockIdx.x;
    const int base = off[e];

    __shared__ unsigned short As[128 * LDS_ST];
    __shared__ unsigned short Bg[128 * LDS_ST];
    __shared__ unsigned short Bu[128 * LDS_ST];

    const int tid  = threadIdx.x;
    const int r    = tid >> 1;
    const int half = tid & 1;

    int ar = mt * 128 + r;
    if (ar >= ce) ar = ce - 1;
    const float* aptr = h + (size_t)tok_row[base + ar] * D_DIM + half * 16;
    const float* bgp  = ws + ((size_t)e * (2 * I_DIM) + (size_t)(nt * 128 + r)) * D_DIM + half * 16;
    const float* bup  = bgp + (size_t)I_DIM * D_DIM;

    unsigned short* aw  = &As[r * LDS_ST + half * 16];
    unsigned short* bgw = &Bg[r * LDS_ST + half * 16];
    unsigned short* buw = &Bu[r * LDS_ST + half * 16];

    const int wave = tid >> 6;
    const int lane = tid & 63;
    const int quad = lane >> 4;
    const int l16  = lane & 15;
    const int wm = (wave >> 1) * 64;
    const int wn = (wave & 1) * 64;

    floatx4 accg[4][4], accu[4][4];
#pragma unroll
    for (int i = 0; i < 4; ++i)
#pragma unroll
        for (int j = 0; j < 4; ++j) { accg[i][j] = (floatx4)0.f; accu[i][j] = (floatx4)0.f; }

    for (int k0 = 0; k0 < D_DIM; k0 += 32) {
        const float4* ap4 = reinterpret_cast<const float4*>(aptr + k0);
        const float4* bg4 = reinterpret_cast<const float4*>(bgp + k0);
        const float4* bu4 = reinterpret_cast<const float4*>(bup + k0);
        float4 a0 = ap4[0], a1 = ap4[1], a2 = ap4[2], a3 = ap4[3];
        float4 g0 = bg4[0], g1 = bg4[1], g2 = bg4[2], g3 = bg4[3];
        float4 u0 = bu4[0], u1 = bu4[1], u2 = bu4[2], u3 = bu4[3];
        __syncthreads();
        *reinterpret_cast<ushort8*>(aw)      = cvt8(a0, a1);
        *reinterpret_cast<ushort8*>(aw + 8)  = cvt8(a2, a3);
        *reinterpret_cast<ushort8*>(bgw)     = cvt8(g0, g1);
        *reinterpret_cast<ushort8*>(bgw + 8) = cvt8(g2, g3);
        *reinterpret_cast<ushort8*>(buw)     = cvt8(u0, u1);
        *reinterpret_cast<ushort8*>(buw + 8) = cvt8(u2, u3);
        __syncthreads();
        short8 a[4], bg[4], bu[4];
#pragma unroll
        for (int i = 0; i < 4; ++i)
            a[i] = *reinterpret_cast<const short8*>(&As[(wm + i * 16 + l16) * LDS_ST + quad * 8]);
#pragma unroll
        for (int j = 0; j < 4; ++j) {
            bg[j] = *reinterpret_cast<const short8*>(&Bg[(wn + j * 16 + l16) * LDS_ST + quad * 8]);
            bu[j] = *reinterpret_cast<const short8*>(&Bu[(wn + j * 16 + l16) * LDS_ST + quad * 8]);
        }
#pragma unroll
        for (int i = 0; i < 4; ++i)
#pragma unroll
            for (int j = 0; j < 4; ++j) {
                accg[i][j] = __builtin_amdgcn_mfma_f32_16x16x32_bf16(a[i], bg[j], accg[i][j], 0, 0, 0);
                accu[i][j] = __builtin_amdgcn_mfma_f32_16x16x32_bf16(a[i], bu[j], accu[i][j], 0, 0, 0);
            }
    }

#pragma unroll
    for (int i = 0; i < 4; ++i) {
#pragma unroll
        for (int reg = 0; reg < 4; ++reg) {
            const int gr = mt * 128 + wm + i * 16 + quad * 4 + reg;
            if (gr < ce) {
                const size_t rowoff = (size_t)(base + gr) * I_DIM;
#pragma unroll
                for (int j = 0; j < 4; ++j) {
                    float g = accg[i][j][reg];
                    float u = accu[i][j][reg];
                    float sa = g * u / (1.f + __expf(-g));
                    act[rowoff + nt * 128 + wn + j * 16 + l16] = f2bf(sa);
                }
            }
        }
    }
}

__global__ __launch_bounds__(256) void down_kernel(
    const unsigned short* __restrict__ act, const float* __restrict__ w2s,
    const int* __restrict__ tok_row, const float* __restrict__ wt_row,
    const int* __restrict__ cnt, const int* __restrict__ off,
    float* __restrict__ out)
{
    const int e  = blockIdx.y >> 6;
    const int mt = blockIdx.y & 63;
    const int ce = cnt[e];
    if (mt * 128 >= ce) return;
    const int nt = blockIdx.x;
    const int base = off[e];

    __shared__ unsigned short As[128 * LDS_ST];
    __shared__ unsigned short Bs[128 * LDS_ST];

    const int tid  = threadIdx.x;
    const int r    = tid >> 1;
    const int half = tid & 1;

    int ar = mt * 128 + r;
    if (ar >= ce) ar = ce - 1;
    const unsigned short* aptr = act + (size_t)(base + ar) * I_DIM + half * 16;
    const float* bp = w2s + ((size_t)e * D_DIM + (size_t)(nt * 128 + r)) * I_DIM + half * 16;

    unsigned short* aw = &As[r * LDS_ST + half * 16];
    unsigned short* bw = &Bs[r * LDS_ST + half * 16];

    const int wave = tid >> 6;
    const int lane = tid & 63;
    const int quad = lane >> 4;
    const int l16  = lane & 15;
    const int wm = (wave >> 1) * 64;
    const int wn = (wave & 1) * 64;

    floatx4 acc[4][4];
#pragma unroll
    for (int i = 0; i < 4; ++i)
#pragma unroll
        for (int j = 0; j < 4; ++j) acc[i][j] = (floatx4)0.f;

    for (int k0 = 0; k0 < I_DIM; k0 += 32) {
        ushort8 av0 = *reinterpret_cast<const ushort8*>(aptr + k0);
        ushort8 av1 = *reinterpret_cast<const ushort8*>(aptr + k0 + 8);
        const float4* b4 = reinterpret_cast<const float4*>(bp + k0);
        float4 b0 = b4[0], b1 = b4[1], b2 = b4[2], b3 = b4[3];
        __syncthreads();
        *reinterpret_cast<ushort8*>(aw)     = av0;
        *reinterpret_cast<ushort8*>(aw + 8) = av1;
        *reinterpret_cast<ushort8*>(bw)     = cvt8(b0, b1);
        *reinterpret_cast<ushort8*>(bw + 8) = cvt8(b2, b3);
        __syncthreads();
        short8 a[4], b[4];
#pragma unroll
        for (int i = 0; i < 4; ++i)
            a[i] = *reinterpret_cast<const short8*>(&As[(wm + i * 16 + l16) * LDS_ST + quad * 8]);
#pragma unroll
        for (int j = 0; j < 4; ++j)
            b[j] = *reinterpret_cast<const short8*>(&Bs[(wn + j * 16 + l16) * LDS_ST + quad * 8]);
#pragma unroll
        for (int i = 0; i < 4; ++i)
#pragma unroll
            for (int j = 0; j < 4; ++j)
                acc[i][j] = __builtin_amdgcn_mfma_f32_16x16x32_bf16(a[i], b[j], acc[i][j], 0, 0, 0);
    }

#pragma unroll
    for (int i = 0; i < 4; ++i) {
#pragma unroll
        for (int reg = 0; reg < 4; ++reg) {
            const int gr = mt * 128 + wm + i * 16 + quad * 4 + reg;
            if (gr < ce) {
                const int tok = tok_row[base + gr];
                const float w = wt_row[base + gr];
                float* op = out + (size_t)tok * D_DIM + nt * 128 + wn;
#pragma unroll
                for (int j = 0; j < 4; ++j)
                    atomicAdd(&op[j * 16 + l16], acc[i][j][reg] * w);
            }
        }
    }
}

extern "C" void kernel_launch(void* const* d_in, const int* in_sizes, int n_in,
                              void* d_out, int out_size, void* d_ws, size_t ws_size,
                              hipStream_t stream)
{
    const float* h   = (const float*)d_in[0];
    const float* rw  = (const float*)d_in[1];
    const float* ws  = (const float*)d_in[2];
    const float* w2s = (const float*)d_in[3];
    float* out = (float*)d_out;

    char* wsp = (char*)d_ws;
    int*   cnt     = (int*)(wsp + 0);
    int*   cnt2    = (int*)(wsp + 32);
    int*   off     = (int*)(wsp + 64);
    int*   topk_id = (int*)(wsp + 256);
    float* topk_w  = (float*)(wsp + 256 + 65536);
    int*   tok_row = (int*)(wsp + 256 + 2 * 65536);
    float* wt_row  = (float*)(wsp + 256 + 3 * 65536);
    const size_t meta = 256 + 4 * 65536;

    unsigned short* act = (unsigned short*)(wsp + meta);           // [2T, I] bf16 = 128 MB
    const size_t actB = (size_t)2 * T_TOK * I_DIM * 2;
    unsigned short* hb   = (unsigned short*)((char*)act + actB);   // [T, D]   bf16 =  32 MB
    const size_t hbB = (size_t)T_TOK * D_DIM * 2;
    unsigned short* wsbf = (unsigned short*)((char*)hb + hbB);     // [E,2I,D] bf16 = 256 MB
    const size_t wsB = (size_t)E_EXP * 2 * I_DIM * D_DIM * 2;
    unsigned short* w2bf = (unsigned short*)((char*)wsbf + wsB);   // [E,D,I]  bf16 = 128 MB
    const size_t w2B = (size_t)E_EXP * D_DIM * I_DIM * 2;
    const size_t need = meta + actB + hbB + wsB + w2B;             // ~544 MB

    hipMemsetAsync(wsp, 0, 256, stream);                                   // cnt/cnt2/off
    hipMemsetAsync(out, 0, (size_t)T_TOK * D_DIM * sizeof(float), stream); // accumulation target

    router_kernel<<<T_TOK / 4, 256, 0, stream>>>(h, rw, topk_id, topk_w);
    count_kernel<<<(2 * T_TOK) / 256, 256, 0, stream>>>(topk_id, cnt);
    prefix_kernel<<<1, 1, 0, stream>>>(cnt, off);
    scatter_kernel<<<(2 * T_TOK) / 256, 256, 0, stream>>>(topk_id, topk_w, off, cnt2, tok_row, wt_row);

    if (ws_size >= need) {
        cvt_kernel<<<2048, 256, 0, stream>>>(h,   hb,   (size_t)T_TOK * D_DIM / 8);
        cvt_kernel<<<2048, 256, 0, stream>>>(ws,  wsbf, (size_t)E_EXP * 2 * I_DIM * D_DIM / 8);
        cvt_kernel<<<2048, 256, 0, stream>>>(w2s, w2bf, (size_t)E_EXP * D_DIM * I_DIM / 8);
        gateup2<<<dim3(I_DIM / 128, E_EXP * NMT), 256, 0, stream>>>(hb, wsbf, tok_row, cnt, off, act);
        down2<<<dim3(D_DIM / 128, E_EXP * NMT), 256, 0, stream>>>(act, w2bf, tok_row, wt_row, cnt, off, out);
    } else {
        gateup_kernel<<<dim3(I_DIM / 128, E_EXP * 64), 256, 0, stream>>>(h, ws, tok_row, cnt, off, act);
        down_kernel<<<dim3(D_DIM / 128, E_EXP * 64), 256, 0, stream>>>(act, w2s, tok_row, wt_row, cnt, off, out);
    }
}